// Round 11
// baseline (265.610 us; speedup 1.0000x reference)
//
#include <hip/hip_runtime.h>
#include <hip/hip_bf16.h>

// Problem constants
#define S_LEN 2048
#define DMODEL 2048
#define NH 16
#define HDIM 128
#define SCALE_F 0.08838834764831845f  // 1/sqrt(128)

typedef __attribute__((ext_vector_type(8))) short bf16x8;  // 8 bf16 = 4 VGPRs
typedef __attribute__((ext_vector_type(4))) float f32x4;

__device__ __forceinline__ unsigned short f2bf(float f) {
  unsigned int u = __float_as_uint(f);
  u += 0x7FFFu + ((u >> 16) & 1u);   // round-to-nearest-even
  return (unsigned short)(u >> 16);
}

__device__ __forceinline__ void gload16(const void* g, void* l) {
  __builtin_amdgcn_global_load_lds(
      (const __attribute__((address_space(1))) unsigned int*)g,
      (__attribute__((address_space(3))) unsigned int*)l, 16, 0, 0);
}

// ---------------- fused fp32 -> bf16 conversion (all 5 tensors) ----------------
__global__ __launch_bounds__(256) void cvt_all(
    const float* __restrict__ x, const float* __restrict__ qw,
    const float* __restrict__ kw, const float* __restrict__ vw,
    const float* __restrict__ ow, unsigned short* __restrict__ xb,
    unsigned short* __restrict__ wqkv, unsigned short* __restrict__ wo) {
  int i = blockIdx.x * blockDim.x + threadIdx.x;  // float4 index
  const float* src;
  unsigned short* dst;
  int off;
  if (i < 2097152) {
    src = x; dst = xb; off = i;
  } else {
    const int j = i - 2097152;
    const int wsel = j >> 20;
    off = j & 1048575;
    src = (wsel == 0) ? qw : (wsel == 1) ? kw : (wsel == 2) ? vw : ow;
    dst = (wsel == 0) ? wqkv
        : (wsel == 1) ? (wqkv + 4194304)
        : (wsel == 2) ? (wqkv + 8388608)
                      : wo;
  }
  const float4 v = *(const float4*)(src + (size_t)off * 4);
  ushort4 o;
  o.x = f2bf(v.x); o.y = f2bf(v.y); o.z = f2bf(v.z); o.w = f2bf(v.w);
  *(ushort4*)(dst + (size_t)off * 4) = o;
}

// ================= 128x256 pipelined GEMM core (3-buffer, T4 counted vmcnt) ==
// (best-measured core, R4). See R4 for the drain ledger.
__device__ __forceinline__ void gemm_core_128x256(
    const unsigned short* __restrict__ Ag, const unsigned short* __restrict__ Wg,
    int m0, int n0, char* lds, int t, f32x4 (&acc)[4][4]) {
  const int lane = t & 63, w = t >> 6;
  const int wr = w >> 2, wc = w & 3;

#pragma unroll
  for (int mi = 0; mi < 4; ++mi)
#pragma unroll
    for (int nj = 0; nj < 4; ++nj)
#pragma unroll
      for (int e = 0; e < 4; ++e) acc[mi][nj][e] = 0.f;

  const int fr = lane & 15;
  const int sw16 = (((lane >> 4) ^ ((lane >> 1) & 3)) << 4);
  const int aRowBase = (wr * 64 + fr) * 64;
  const int bRowBase = (wc * 64 + fr) * 64;

  const int cg8 = (((t & 3) ^ ((t >> 3) & 3)) * 8);
  const unsigned short* sAbase = Ag + (m0 + (t >> 2)) * DMODEL + cg8;
  const unsigned short* sBbase0 = Wg + (n0 + (t >> 2)) * DMODEL + cg8;
  const unsigned short* sBbase1 = sBbase0 + 128 * DMODEL;
  char* dstW = lds + w * 1024;

  auto stage3 = [&](int Tc, int h, int buf) {
    const int koff = Tc * 64 + h * 32;
    gload16(sAbase + koff, dstW + buf * 16384 + h * 8192);
    gload16(sBbase0 + koff, dstW + 49152 + buf * 32768 + h * 16384);
    gload16(sBbase1 + koff, dstW + 49152 + buf * 32768 + h * 16384 + 8192);
  };

  auto phase = [&](int h, int bufR, int doStage, int TS, int bufS, int vm) {
    const int rA = bufR * 16384 + h * 8192;
    const int rB = 49152 + bufR * 32768 + h * 16384;
    bf16x8 a[4], b[4];
#pragma unroll
    for (int mi = 0; mi < 4; ++mi)
      a[mi] = *(const bf16x8*)(lds + rA + aRowBase + mi * 1024 + sw16);
#pragma unroll
    for (int nj = 0; nj < 4; ++nj)
      b[nj] = *(const bf16x8*)(lds + rB + bRowBase + nj * 1024 + sw16);
    if (doStage) stage3(TS, h, bufS);
    if (vm == 6) asm volatile("s_waitcnt vmcnt(6)" ::: "memory");
    if (vm == 0) asm volatile("s_waitcnt vmcnt(0)" ::: "memory");
    __builtin_amdgcn_s_barrier();
    __builtin_amdgcn_s_setprio(1);
#pragma unroll
    for (int mi = 0; mi < 4; ++mi)
#pragma unroll
      for (int nj = 0; nj < 4; ++nj)
        acc[mi][nj] = __builtin_amdgcn_mfma_f32_16x16x32_bf16(
            a[mi], b[nj], acc[mi][nj], 0, 0, 0);
    __builtin_amdgcn_s_setprio(0);
    __builtin_amdgcn_s_barrier();
  };

  stage3(0, 0, 0);
  stage3(0, 1, 0);
  stage3(1, 0, 1);
  stage3(1, 1, 1);
  asm volatile("s_waitcnt vmcnt(6)" ::: "memory");
  __builtin_amdgcn_s_barrier();

#pragma unroll 1
  for (int k3 = 0; k3 < 10; ++k3) {
    const int T = k3 * 3;
    phase(0, 0, 1, T + 2, 2, -1);
    phase(1, 0, 1, T + 2, 2, 6);
    phase(0, 1, 1, T + 3, 0, -1);
    phase(1, 1, 1, T + 3, 0, 6);
    phase(0, 2, 1, T + 4, 1, -1);
    phase(1, 2, 1, T + 4, 1, 6);
  }
  phase(0, 0, 0, 0, 0, -1);
  phase(1, 0, 0, 0, 0, 0);
  phase(0, 1, 0, 0, 0, -1);
  phase(1, 1, 0, 0, 0, -1);
}

// ---------------- QKV projection GEMM (M=4096, N=6144) ----------------
// Direct stores everywhere (R4 config — measured fastest).
__global__ __launch_bounds__(512, 1) void gemm_qkv(
    const unsigned short* __restrict__ A, const unsigned short* __restrict__ W,
    const float* __restrict__ qbias, const float* __restrict__ kbias,
    const float* __restrict__ vbias,
    unsigned short* __restrict__ qo, unsigned short* __restrict__ ko,
    unsigned short* __restrict__ vto) {
  extern __shared__ char lds[];
  const int t = threadIdx.x;
  const int swz = ((int)blockIdx.x & 7) * 96 + ((int)blockIdx.x >> 3);
  const int m0 = (swz & 31) * 128;
  const int n0 = (swz >> 5) * 256;

  f32x4 acc[4][4];
  gemm_core_128x256(A, W, m0, n0, lds, t, acc);

  const int lane = t & 63, w = t >> 6;
  const int wr = w >> 2, wc = w & 3;
  const int b_ = m0 >> 11;
  const int proj = n0 >> 11;  // uniform per block (2048 % 256 == 0)
  const int nn_base = (n0 & 2047) + wc * 64;
  const float* bias = (proj == 0) ? qbias : ((proj == 1) ? kbias : vbias);
#pragma unroll
  for (int nj = 0; nj < 4; ++nj) {
    const int nn = nn_base + nj * 16 + (lane & 15);
    const int h = nn >> 7, hd = nn & 127;
    const float bv = bias[nn];
#pragma unroll
    for (int mi = 0; mi < 4; ++mi) {
      const int mrow = m0 + wr * 64 + mi * 16 + (lane >> 4) * 4;
      const int s = mrow & 2047;
      if (proj == 2) {
        // V^T: [(b*NH+h)*HDIM + hd][S], 4 consecutive s -> one 8B store
        unsigned short* dst = vto + ((b_ * NH + h) * HDIM + hd) * S_LEN + s;
        ushort4 pk;
        pk.x = f2bf(acc[mi][nj][0] + bv);
        pk.y = f2bf(acc[mi][nj][1] + bv);
        pk.z = f2bf(acc[mi][nj][2] + bv);
        pk.w = f2bf(acc[mi][nj][3] + bv);
        *(ushort4*)dst = pk;
      } else {
        unsigned short* dst =
            ((proj == 0) ? qo : ko) + ((b_ * NH + h) * S_LEN + s) * HDIM + hd;
#pragma unroll
        for (int r = 0; r < 4; r++) dst[r * HDIM] = f2bf(acc[mi][nj][r] + bv);
      }
    }
  }
}

// ---------------- output projection GEMM (M=4096, N=2048) ----------------
__global__ __launch_bounds__(512, 1) void gemm_out(
    const unsigned short* __restrict__ A, const unsigned short* __restrict__ W,
    const float* __restrict__ bias, float* __restrict__ out) {
  extern __shared__ char lds[];
  const int t = threadIdx.x;
  const int swz = ((int)blockIdx.x & 7) * 32 + ((int)blockIdx.x >> 3);
  const int m0 = (swz & 31) * 128;
  const int n0 = (swz >> 5) * 256;

  f32x4 acc[4][4];
  gemm_core_128x256(A, W, m0, n0, lds, t, acc);

  const int lane = t & 63, w = t >> 6;
  const int wr = w >> 2, wc = w & 3;
#pragma unroll
  for (int nj = 0; nj < 4; ++nj) {
    const int n = n0 + wc * 64 + nj * 16 + (lane & 15);
    const float bv = bias[n];
#pragma unroll
    for (int mi = 0; mi < 4; ++mi) {
      const int mrow = m0 + wr * 64 + mi * 16 + (lane >> 4) * 4;
      float* dst = out + (size_t)mrow * DMODEL + n;
#pragma unroll
      for (int r = 0; r < 4; r++) dst[r * DMODEL] = acc[mi][nj][r] + bv;
    }
  }
}

// ---------------- causal flash attention (R8 softmax, 4 blocks/CU) ----------
// 1024 blocks, ONE q-tile each (4 blocks/CU resident: VGPR 112<=128, LDS
// 4x40KB=160KB). XCD k (bid%8) owns bh in {4k..4k+3}. qtile = perm(bid>>5)
// with perm(g*8+r) = {r, 15-r, 16+r, 31-r}: under round-robin dispatch CU c
// receives qtile classes {q,q+8,q+16,q+24} whose permuted work sums to a
// UNIFORM 66 tile-units per CU — per-CU balance of the paired layout with
// 2x the resident waves (latency-bound fix; heuristic on dispatch order,
// correctness unaffected).
__global__ __launch_bounds__(256, 4) void attn_fwd(
    const unsigned short* __restrict__ Q,   // [B*H][S][128]
    const unsigned short* __restrict__ K,   // [B*H][S][128]
    const unsigned short* __restrict__ VT,  // [B*H][128][S]
    unsigned short* __restrict__ ctx) {     // [B][S][2048]
  __shared__ unsigned short Ks[2][64 * 128];   // 2x16 KB, row-swizzled
  __shared__ unsigned short Vs[2][128 * 64];   // 2x16 KB, V^T tile, swizzled
  __shared__ unsigned short Ps[4][16 * 64];    // 8 KB, per-wave P, swizzled
  const int t = threadIdx.x, lane = t & 63, w = t >> 6;
  const int bid = blockIdx.x;
  const int bh = ((bid & 7) << 2) + ((bid >> 3) & 3);  // XCD-locality map
  const int qi = bid >> 5;                             // [0,32)
  const int g = qi >> 3, r_ = qi & 7;
  const int qtile = (g == 0) ? r_ : (g == 1) ? (15 - r_)
                  : (g == 2) ? (16 + r_) : (31 - r_);
  const unsigned short* Qb = Q + bh * (S_LEN * HDIM);
  const unsigned short* Kb = K + bh * (S_LEN * HDIM);
  const unsigned short* Vb = VT + bh * (HDIM * S_LEN);
  const int b_ = bh >> 4, h = bh & 15;

  auto stageKV = [&](int buf, int kv0) {
#pragma unroll
    for (int u = 0; u < 4; ++u) {
      const int c = t + u * 256;
      const int row = c >> 4, cc = c & 15;
      gload16(Kb + (kv0 + row) * HDIM + ((cc ^ (row & 7)) * 8),
              (char*)Ks[buf] + u * 4096 + w * 1024);
    }
#pragma unroll
    for (int u = 0; u < 4; ++u) {
      const int c = t + u * 256;
      const int row = c >> 3, cc = c & 7;
      gload16(Vb + row * S_LEN + kv0 + ((cc ^ (row & 7)) * 8),
              (char*)Vs[buf] + u * 4096 + w * 1024);
    }
  };

  const int q0 = qtile * 64 + w * 16;

  // Q fragments: A-operand row = lane&15, k = dk*32 + 8*(lane>>4)
  bf16x8 qf[4];
  {
    const unsigned short* qrow =
        Qb + (q0 + (lane & 15)) * HDIM + (lane >> 4) * 8;
#pragma unroll
    for (int dk = 0; dk < 4; dk++) qf[dk] = *(const bf16x8*)(qrow + dk * 32);
  }

  float mrow[4], lrow[4];
  f32x4 oacc[8];
#pragma unroll
  for (int r = 0; r < 4; r++) { mrow[r] = -__builtin_inff(); lrow[r] = 0.f; }
#pragma unroll
  for (int d = 0; d < 8; d++)
#pragma unroll
    for (int e = 0; e < 4; e++) oacc[d][e] = 0.f;

  const int nt = qtile + 1;
  stageKV(0, 0);
  __syncthreads();  // drain prologue stage
  int cur = 0;

#pragma unroll 1
  for (int kt = 0; kt < nt; ++kt) {
    // issue next tile's loads first; they complete under this tile's compute
    if (kt + 1 < nt) stageKV(cur ^ 1, (kt + 1) * 64);

    const unsigned short* Kc = Ks[cur];
    const unsigned short* Vc = Vs[cur];
    const int kv0 = kt * 64;

    // S = Q K^T  (16 q-rows x 64 kv-cols)
    f32x4 sacc[4];
#pragma unroll
    for (int ck = 0; ck < 4; ck++)
#pragma unroll
      for (int e = 0; e < 4; e++) sacc[ck][e] = 0.f;
    __builtin_amdgcn_s_setprio(1);
#pragma unroll
    for (int ck = 0; ck < 4; ++ck) {
      const int krow = ck * 16 + (lane & 15);
#pragma unroll
      for (int dk = 0; dk < 4; ++dk) {
        const int chunk = dk * 4 + (lane >> 4);
        const bf16x8 kf = *(const bf16x8*)((const char*)Kc + krow * 256 +
                                           ((chunk ^ (krow & 7)) << 4));
        sacc[ck] = __builtin_amdgcn_mfma_f32_16x16x32_bf16(qf[dk], kf,
                                                           sacc[ck], 0, 0, 0);
      }
    }
    __builtin_amdgcn_s_setprio(0);
    // scale + causal mask (diagonal tile only)
#pragma unroll
    for (int ck = 0; ck < 4; ck++)
#pragma unroll
      for (int r = 0; r < 4; r++) sacc[ck][r] *= SCALE_F;
    if (kt == qtile) {
#pragma unroll
      for (int ck = 0; ck < 4; ck++) {
        const int col = kv0 + ck * 16 + (lane & 15);
#pragma unroll
        for (int r = 0; r < 4; r++) {
          const int rowq = q0 + (lane >> 4) * 4 + r;
          if (col > rowq) sacc[ck][r] = -__builtin_inff();
        }
      }
    }
    // per-lane local row max; full 16-shfl reduce only if growth > 8
    float pm[4];
#pragma unroll
    for (int r = 0; r < 4; r++)
      pm[r] = fmaxf(fmaxf(sacc[0][r], sacc[1][r]),
                    fmaxf(sacc[2][r], sacc[3][r]));
    bool need = false;
#pragma unroll
    for (int r = 0; r < 4; r++) need |= (pm[r] > mrow[r] + 8.f);
    if (__any(need)) {
#pragma unroll
      for (int off = 1; off < 16; off <<= 1)
#pragma unroll
        for (int r = 0; r < 4; r++)
          pm[r] = fmaxf(pm[r], __shfl_xor(pm[r], off, 64));
#pragma unroll
      for (int r = 0; r < 4; r++) {
        const float mn = fmaxf(mrow[r], pm[r]);
        const float corr = __expf(mrow[r] - mn);  // 0 on first tile
        mrow[r] = mn;
        lrow[r] *= corr;
#pragma unroll
        for (int d = 0; d < 8; d++) oacc[d][r] *= corr;
      }
    }
#pragma unroll
    for (int ck = 0; ck < 4; ck++)
#pragma unroll
      for (int r = 0; r < 4; r++) {
        const float p = __expf(sacc[ck][r] - mrow[r]);  // masked -> 0
        lrow[r] += p;  // per-lane partial; reduced once at epilogue
        const int prow = (lane >> 4) * 4 + r;
        const int pcol = ck * 16 + (lane & 15);
        *(unsigned short*)((char*)Ps[w] +
                           ((prow * 128 + pcol * 2) ^ ((prow & 7) << 4))) =
            f2bf(p);
      }

    // O += P V : A = P [16 q][64 k], B = V [64 k][128 d] (from V^T tile)
    bf16x8 pf[2];
    {
      const int prow = lane & 15;
#pragma unroll
      for (int kk = 0; kk < 2; kk++) {
        const int chunk = kk * 4 + (lane >> 4);
        pf[kk] = *(const bf16x8*)((const char*)Ps[w] + prow * 128 +
                                  ((chunk ^ (prow & 7)) << 4));
      }
    }
    __builtin_amdgcn_s_setprio(1);
#pragma unroll
    for (int d = 0; d < 8; ++d) {
      const int vrow = d * 16 + (lane & 15);
#pragma unroll
      for (int kk = 0; kk < 2; ++kk) {
        const int chunk = kk * 4 + (lane >> 4);
        const bf16x8 vf = *(const bf16x8*)((const char*)Vc + vrow * 128 +
                                           ((chunk ^ (vrow & 7)) << 4));
        oacc[d] = __builtin_amdgcn_mfma_f32_16x16x32_bf16(pf[kk], vf, oacc[d],
                                                          0, 0, 0);
      }
    }
    __builtin_amdgcn_s_setprio(0);

    __syncthreads();  // prefetch drained here; buffers swap
    cur ^= 1;
  }

  // epilogue: one l-reduce across the 16 col-lanes, then store
#pragma unroll
  for (int off = 1; off < 16; off <<= 1)
#pragma unroll
    for (int r = 0; r < 4; r++) lrow[r] += __shfl_xor(lrow[r], off, 64);
#pragma unroll
  for (int r = 0; r < 4; r++) {
    const float inv = 1.f / lrow[r];
    const int srow = q0 + (lane >> 4) * 4 + r;
    unsigned short* dst =
        ctx + (b_ * S_LEN + srow) * DMODEL + h * HDIM + (lane & 15);
#pragma unroll
    for (int d = 0; d < 8; d++) dst[d * 16] = f2bf(oacc[d][r] * inv);
  }
}

// ---------------- host launcher ----------------
extern "C" void kernel_launch(void* const* d_in, const int* in_sizes, int n_in,
                              void* d_out, int out_size, void* d_ws,
                              size_t ws_size, hipStream_t stream) {
  const float* x  = (const float*)d_in[0];
  const float* qw = (const float*)d_in[1];
  const float* qb = (const float*)d_in[2];
  const float* kw = (const float*)d_in[3];
  const float* kb = (const float*)d_in[4];
  const float* vw = (const float*)d_in[5];
  const float* vb = (const float*)d_in[6];
  const float* ow = (const float*)d_in[7];
  const float* ob = (const float*)d_in[8];
  float* out = (float*)d_out;

  // workspace layout (bf16 elements); total 117,440,512 bytes
  unsigned short* xb   = (unsigned short*)d_ws;        // x      [4096][2048]
  unsigned short* wqkv = xb + (size_t)8388608;         // [6144][2048]
  unsigned short* wo   = wqkv + (size_t)12582912;      // [2048][2048]
  unsigned short* qt_  = wo + (size_t)4194304;         // Q  [B,H,S,HD]
  unsigned short* kt_  = qt_ + (size_t)8388608;        // K  [B,H,S,HD]
  unsigned short* vt_  = kt_ + (size_t)8388608;        // V^T[B,H,HD,S]
  unsigned short* ctx  = vt_ + (size_t)8388608;        // ctx[B,S,D]

  cvt_all<<<24576, 256, 0, stream>>>(x, qw, kw, vw, ow, xb, wqkv, wo);

  gemm_qkv<<<768, 512, 147456, stream>>>(xb, wqkv, qb, kb, vb, qt_, kt_, vt_);
  attn_fwd<<<1024, 256, 0, stream>>>(qt_, kt_, vt_, ctx);
  gemm_out<<<256, 512, 147456, stream>>>(ctx, wo, ob, out);
}

// Round 12
// 256.426 us; speedup vs baseline: 1.0358x; 1.0358x over previous
//
#include <hip/hip_runtime.h>
#include <hip/hip_bf16.h>

// Problem constants
#define S_LEN 2048
#define DMODEL 2048
#define NH 16
#define HDIM 128
#define SCALE_F 0.08838834764831845f  // 1/sqrt(128)

typedef __attribute__((ext_vector_type(8))) short bf16x8;  // 8 bf16 = 4 VGPRs
typedef __attribute__((ext_vector_type(4))) float f32x4;

__device__ __forceinline__ unsigned short f2bf(float f) {
  unsigned int u = __float_as_uint(f);
  u += 0x7FFFu + ((u >> 16) & 1u);   // round-to-nearest-even
  return (unsigned short)(u >> 16);
}

__device__ __forceinline__ void gload16(const void* g, void* l) {
  __builtin_amdgcn_global_load_lds(
      (const __attribute__((address_space(1))) unsigned int*)g,
      (__attribute__((address_space(3))) unsigned int*)l, 16, 0, 0);
}

// ---------------- fused fp32 -> bf16 conversion (all 5 tensors) ----------------
__global__ __launch_bounds__(256) void cvt_all(
    const float* __restrict__ x, const float* __restrict__ qw,
    const float* __restrict__ kw, const float* __restrict__ vw,
    const float* __restrict__ ow, unsigned short* __restrict__ xb,
    unsigned short* __restrict__ wqkv, unsigned short* __restrict__ wo) {
  int i = blockIdx.x * blockDim.x + threadIdx.x;  // float4 index
  const float* src;
  unsigned short* dst;
  int off;
  if (i < 2097152) {
    src = x; dst = xb; off = i;
  } else {
    const int j = i - 2097152;
    const int wsel = j >> 20;
    off = j & 1048575;
    src = (wsel == 0) ? qw : (wsel == 1) ? kw : (wsel == 2) ? vw : ow;
    dst = (wsel == 0) ? wqkv
        : (wsel == 1) ? (wqkv + 4194304)
        : (wsel == 2) ? (wqkv + 8388608)
                      : wo;
  }
  const float4 v = *(const float4*)(src + (size_t)off * 4);
  ushort4 o;
  o.x = f2bf(v.x); o.y = f2bf(v.y); o.z = f2bf(v.z); o.w = f2bf(v.w);
  *(ushort4*)(dst + (size_t)off * 4) = o;
}

// ================= 128x256 pipelined GEMM core (3-buffer, T4 counted vmcnt) ==
// (best-measured core, R4). See R4 for the drain ledger.
__device__ __forceinline__ void gemm_core_128x256(
    const unsigned short* __restrict__ Ag, const unsigned short* __restrict__ Wg,
    int m0, int n0, char* lds, int t, f32x4 (&acc)[4][4]) {
  const int lane = t & 63, w = t >> 6;
  const int wr = w >> 2, wc = w & 3;

#pragma unroll
  for (int mi = 0; mi < 4; ++mi)
#pragma unroll
    for (int nj = 0; nj < 4; ++nj)
#pragma unroll
      for (int e = 0; e < 4; ++e) acc[mi][nj][e] = 0.f;

  const int fr = lane & 15;
  const int sw16 = (((lane >> 4) ^ ((lane >> 1) & 3)) << 4);
  const int aRowBase = (wr * 64 + fr) * 64;
  const int bRowBase = (wc * 64 + fr) * 64;

  const int cg8 = (((t & 3) ^ ((t >> 3) & 3)) * 8);
  const unsigned short* sAbase = Ag + (m0 + (t >> 2)) * DMODEL + cg8;
  const unsigned short* sBbase0 = Wg + (n0 + (t >> 2)) * DMODEL + cg8;
  const unsigned short* sBbase1 = sBbase0 + 128 * DMODEL;
  char* dstW = lds + w * 1024;

  auto stage3 = [&](int Tc, int h, int buf) {
    const int koff = Tc * 64 + h * 32;
    gload16(sAbase + koff, dstW + buf * 16384 + h * 8192);
    gload16(sBbase0 + koff, dstW + 49152 + buf * 32768 + h * 16384);
    gload16(sBbase1 + koff, dstW + 49152 + buf * 32768 + h * 16384 + 8192);
  };

  auto phase = [&](int h, int bufR, int doStage, int TS, int bufS, int vm) {
    const int rA = bufR * 16384 + h * 8192;
    const int rB = 49152 + bufR * 32768 + h * 16384;
    bf16x8 a[4], b[4];
#pragma unroll
    for (int mi = 0; mi < 4; ++mi)
      a[mi] = *(const bf16x8*)(lds + rA + aRowBase + mi * 1024 + sw16);
#pragma unroll
    for (int nj = 0; nj < 4; ++nj)
      b[nj] = *(const bf16x8*)(lds + rB + bRowBase + nj * 1024 + sw16);
    if (doStage) stage3(TS, h, bufS);
    if (vm == 6) asm volatile("s_waitcnt vmcnt(6)" ::: "memory");
    if (vm == 0) asm volatile("s_waitcnt vmcnt(0)" ::: "memory");
    __builtin_amdgcn_s_barrier();
    __builtin_amdgcn_s_setprio(1);
#pragma unroll
    for (int mi = 0; mi < 4; ++mi)
#pragma unroll
      for (int nj = 0; nj < 4; ++nj)
        acc[mi][nj] = __builtin_amdgcn_mfma_f32_16x16x32_bf16(
            a[mi], b[nj], acc[mi][nj], 0, 0, 0);
    __builtin_amdgcn_s_setprio(0);
    __builtin_amdgcn_s_barrier();
  };

  stage3(0, 0, 0);
  stage3(0, 1, 0);
  stage3(1, 0, 1);
  stage3(1, 1, 1);
  asm volatile("s_waitcnt vmcnt(6)" ::: "memory");
  __builtin_amdgcn_s_barrier();

#pragma unroll 1
  for (int k3 = 0; k3 < 10; ++k3) {
    const int T = k3 * 3;
    phase(0, 0, 1, T + 2, 2, -1);
    phase(1, 0, 1, T + 2, 2, 6);
    phase(0, 1, 1, T + 3, 0, -1);
    phase(1, 1, 1, T + 3, 0, 6);
    phase(0, 2, 1, T + 4, 1, -1);
    phase(1, 2, 1, T + 4, 1, 6);
  }
  phase(0, 0, 0, 0, 0, -1);
  phase(1, 0, 0, 0, 0, 0);
  phase(0, 1, 0, 0, 0, -1);
  phase(1, 1, 0, 0, 0, -1);
}

// ---------------- QKV projection GEMM (M=4096, N=6144) ----------------
// Direct stores everywhere (R4 config — measured fastest).
__global__ __launch_bounds__(512, 1) void gemm_qkv(
    const unsigned short* __restrict__ A, const unsigned short* __restrict__ W,
    const float* __restrict__ qbias, const float* __restrict__ kbias,
    const float* __restrict__ vbias,
    unsigned short* __restrict__ qo, unsigned short* __restrict__ ko,
    unsigned short* __restrict__ vto) {
  extern __shared__ char lds[];
  const int t = threadIdx.x;
  const int swz = ((int)blockIdx.x & 7) * 96 + ((int)blockIdx.x >> 3);
  const int m0 = (swz & 31) * 128;
  const int n0 = (swz >> 5) * 256;

  f32x4 acc[4][4];
  gemm_core_128x256(A, W, m0, n0, lds, t, acc);

  const int lane = t & 63, w = t >> 6;
  const int wr = w >> 2, wc = w & 3;
  const int b_ = m0 >> 11;
  const int proj = n0 >> 11;  // uniform per block (2048 % 256 == 0)
  const int nn_base = (n0 & 2047) + wc * 64;
  const float* bias = (proj == 0) ? qbias : ((proj == 1) ? kbias : vbias);
#pragma unroll
  for (int nj = 0; nj < 4; ++nj) {
    const int nn = nn_base + nj * 16 + (lane & 15);
    const int h = nn >> 7, hd = nn & 127;
    const float bv = bias[nn];
#pragma unroll
    for (int mi = 0; mi < 4; ++mi) {
      const int mrow = m0 + wr * 64 + mi * 16 + (lane >> 4) * 4;
      const int s = mrow & 2047;
      if (proj == 2) {
        // V^T: [(b*NH+h)*HDIM + hd][S], 4 consecutive s -> one 8B store
        unsigned short* dst = vto + ((b_ * NH + h) * HDIM + hd) * S_LEN + s;
        ushort4 pk;
        pk.x = f2bf(acc[mi][nj][0] + bv);
        pk.y = f2bf(acc[mi][nj][1] + bv);
        pk.z = f2bf(acc[mi][nj][2] + bv);
        pk.w = f2bf(acc[mi][nj][3] + bv);
        *(ushort4*)dst = pk;
      } else {
        unsigned short* dst =
            ((proj == 0) ? qo : ko) + ((b_ * NH + h) * S_LEN + s) * HDIM + hd;
#pragma unroll
        for (int r = 0; r < 4; r++) dst[r * HDIM] = f2bf(acc[mi][nj][r] + bv);
      }
    }
  }
}

// ---------------- output projection GEMM (M=4096, N=2048) ----------------
__global__ __launch_bounds__(512, 1) void gemm_out(
    const unsigned short* __restrict__ A, const unsigned short* __restrict__ W,
    const float* __restrict__ bias, float* __restrict__ out) {
  extern __shared__ char lds[];
  const int t = threadIdx.x;
  const int swz = ((int)blockIdx.x & 7) * 32 + ((int)blockIdx.x >> 3);
  const int m0 = (swz & 31) * 128;
  const int n0 = (swz >> 5) * 256;

  f32x4 acc[4][4];
  gemm_core_128x256(A, W, m0, n0, lds, t, acc);

  const int lane = t & 63, w = t >> 6;
  const int wr = w >> 2, wc = w & 3;
#pragma unroll
  for (int nj = 0; nj < 4; ++nj) {
    const int n = n0 + wc * 64 + nj * 16 + (lane & 15);
    const float bv = bias[n];
#pragma unroll
    for (int mi = 0; mi < 4; ++mi) {
      const int mrow = m0 + wr * 64 + mi * 16 + (lane >> 4) * 4;
      float* dst = out + (size_t)mrow * DMODEL + n;
#pragma unroll
      for (int r = 0; r < 4; r++) dst[r * DMODEL] = acc[mi][nj][r] + bv;
    }
  }
}

// ---------------- causal flash attention (R8 best config) ----------
// 512 blocks; XCD k (bid%8) owns bh in {4k..4k+3} (KV stream L2-local).
// Block handles q-tiles x and 31-x (uniform 33 KV-iterations). 4 waves x
// 16 q-rows, KV tiles of 64, double-buffered staging. l-sum deferred to
// epilogue. Row-max reduce skipped entirely when no lane's local max exceeds
// mrow+8 (exact: mrow is uniform across the 16 row-lanes).
__global__ __launch_bounds__(256, 2) void attn_fwd(
    const unsigned short* __restrict__ Q,   // [B*H][S][128]
    const unsigned short* __restrict__ K,   // [B*H][S][128]
    const unsigned short* __restrict__ VT,  // [B*H][128][S]
    unsigned short* __restrict__ ctx) {     // [B][S][2048]
  __shared__ unsigned short Ks[2][64 * 128];   // 2x16 KB, row-swizzled
  __shared__ unsigned short Vs[2][128 * 64];   // 2x16 KB, V^T tile, swizzled
  __shared__ unsigned short Ps[4][16 * 64];    // 8 KB, per-wave P, swizzled
  const int t = threadIdx.x, lane = t & 63, w = t >> 6;
  const int bid = blockIdx.x;
  const int bh = ((bid & 7) << 2) + ((bid >> 3) & 3);  // XCD-locality map
  const int xq = bid >> 5;
  const unsigned short* Qb = Q + bh * (S_LEN * HDIM);
  const unsigned short* Kb = K + bh * (S_LEN * HDIM);
  const unsigned short* Vb = VT + bh * (HDIM * S_LEN);
  const int b_ = bh >> 4, h = bh & 15;

  auto stageKV = [&](int buf, int kv0) {
#pragma unroll
    for (int u = 0; u < 4; ++u) {
      const int c = t + u * 256;
      const int row = c >> 4, cc = c & 15;
      gload16(Kb + (kv0 + row) * HDIM + ((cc ^ (row & 7)) * 8),
              (char*)Ks[buf] + u * 4096 + w * 1024);
    }
#pragma unroll
    for (int u = 0; u < 4; ++u) {
      const int c = t + u * 256;
      const int row = c >> 3, cc = c & 7;
      gload16(Vb + row * S_LEN + kv0 + ((cc ^ (row & 7)) * 8),
              (char*)Vs[buf] + u * 4096 + w * 1024);
    }
  };

#pragma unroll 1
  for (int pi = 0; pi < 2; ++pi) {
    const int qtile = pi ? (31 - xq) : xq;
    const int q0 = qtile * 64 + w * 16;

    // Q fragments: A-operand row = lane&15, k = dk*32 + 8*(lane>>4)
    bf16x8 qf[4];
    {
      const unsigned short* qrow =
          Qb + (q0 + (lane & 15)) * HDIM + (lane >> 4) * 8;
#pragma unroll
      for (int dk = 0; dk < 4; dk++) qf[dk] = *(const bf16x8*)(qrow + dk * 32);
    }

    float mrow[4], lrow[4];
    f32x4 oacc[8];
#pragma unroll
    for (int r = 0; r < 4; r++) { mrow[r] = -__builtin_inff(); lrow[r] = 0.f; }
#pragma unroll
    for (int d = 0; d < 8; d++)
#pragma unroll
      for (int e = 0; e < 4; e++) oacc[d][e] = 0.f;

    const int nt = qtile + 1;
    stageKV(0, 0);
    __syncthreads();  // drain prologue stage
    int cur = 0;

#pragma unroll 1
    for (int kt = 0; kt < nt; ++kt) {
      // issue next tile's loads first; they complete under this tile's compute
      if (kt + 1 < nt) stageKV(cur ^ 1, (kt + 1) * 64);

      const unsigned short* Kc = Ks[cur];
      const unsigned short* Vc = Vs[cur];
      const int kv0 = kt * 64;

      // S = Q K^T  (16 q-rows x 64 kv-cols)
      f32x4 sacc[4];
#pragma unroll
      for (int ck = 0; ck < 4; ck++)
#pragma unroll
        for (int e = 0; e < 4; e++) sacc[ck][e] = 0.f;
      __builtin_amdgcn_s_setprio(1);
#pragma unroll
      for (int ck = 0; ck < 4; ++ck) {
        const int krow = ck * 16 + (lane & 15);
#pragma unroll
        for (int dk = 0; dk < 4; ++dk) {
          const int chunk = dk * 4 + (lane >> 4);
          const bf16x8 kf = *(const bf16x8*)((const char*)Kc + krow * 256 +
                                             ((chunk ^ (krow & 7)) << 4));
          sacc[ck] = __builtin_amdgcn_mfma_f32_16x16x32_bf16(qf[dk], kf,
                                                             sacc[ck], 0, 0, 0);
        }
      }
      __builtin_amdgcn_s_setprio(0);
      // scale + causal mask (diagonal tile only)
#pragma unroll
      for (int ck = 0; ck < 4; ck++)
#pragma unroll
        for (int r = 0; r < 4; r++) sacc[ck][r] *= SCALE_F;
      if (kt == qtile) {
#pragma unroll
        for (int ck = 0; ck < 4; ck++) {
          const int col = kv0 + ck * 16 + (lane & 15);
#pragma unroll
          for (int r = 0; r < 4; r++) {
            const int rowq = q0 + (lane >> 4) * 4 + r;
            if (col > rowq) sacc[ck][r] = -__builtin_inff();
          }
        }
      }
      // per-lane local row max; full 16-shfl reduce only if growth > 8
      float pm[4];
#pragma unroll
      for (int r = 0; r < 4; r++)
        pm[r] = fmaxf(fmaxf(sacc[0][r], sacc[1][r]),
                      fmaxf(sacc[2][r], sacc[3][r]));
      bool need = false;
#pragma unroll
      for (int r = 0; r < 4; r++) need |= (pm[r] > mrow[r] + 8.f);
      if (__any(need)) {
#pragma unroll
        for (int off = 1; off < 16; off <<= 1)
#pragma unroll
          for (int r = 0; r < 4; r++)
            pm[r] = fmaxf(pm[r], __shfl_xor(pm[r], off, 64));
#pragma unroll
        for (int r = 0; r < 4; r++) {
          const float mn = fmaxf(mrow[r], pm[r]);
          const float corr = __expf(mrow[r] - mn);  // 0 on first tile
          mrow[r] = mn;
          lrow[r] *= corr;
#pragma unroll
          for (int d = 0; d < 8; d++) oacc[d][r] *= corr;
        }
      }
#pragma unroll
      for (int ck = 0; ck < 4; ck++)
#pragma unroll
        for (int r = 0; r < 4; r++) {
          const float p = __expf(sacc[ck][r] - mrow[r]);  // masked -> 0
          lrow[r] += p;  // per-lane partial; reduced once at epilogue
          const int prow = (lane >> 4) * 4 + r;
          const int pcol = ck * 16 + (lane & 15);
          *(unsigned short*)((char*)Ps[w] +
                             ((prow * 128 + pcol * 2) ^ ((prow & 7) << 4))) =
              f2bf(p);
        }

      // O += P V : A = P [16 q][64 k], B = V [64 k][128 d] (from V^T tile)
      bf16x8 pf[2];
      {
        const int prow = lane & 15;
#pragma unroll
        for (int kk = 0; kk < 2; kk++) {
          const int chunk = kk * 4 + (lane >> 4);
          pf[kk] = *(const bf16x8*)((const char*)Ps[w] + prow * 128 +
                                    ((chunk ^ (prow & 7)) << 4));
        }
      }
      __builtin_amdgcn_s_setprio(1);
#pragma unroll
      for (int d = 0; d < 8; ++d) {
        const int vrow = d * 16 + (lane & 15);
#pragma unroll
        for (int kk = 0; kk < 2; ++kk) {
          const int chunk = kk * 4 + (lane >> 4);
          const bf16x8 vf = *(const bf16x8*)((const char*)Vc + vrow * 128 +
                                             ((chunk ^ (vrow & 7)) << 4));
          oacc[d] = __builtin_amdgcn_mfma_f32_16x16x32_bf16(pf[kk], vf, oacc[d],
                                                            0, 0, 0);
        }
      }
      __builtin_amdgcn_s_setprio(0);

      __syncthreads();  // prefetch drained here; buffers swap
      cur ^= 1;
    }

    // epilogue: one l-reduce across the 16 col-lanes, then store
#pragma unroll
    for (int off = 1; off < 16; off <<= 1)
#pragma unroll
      for (int r = 0; r < 4; r++) lrow[r] += __shfl_xor(lrow[r], off, 64);
#pragma unroll
    for (int r = 0; r < 4; r++) {
      const float inv = 1.f / lrow[r];
      const int srow = q0 + (lane >> 4) * 4 + r;
      unsigned short* dst =
          ctx + (b_ * S_LEN + srow) * DMODEL + h * HDIM + (lane & 15);
#pragma unroll
      for (int d = 0; d < 8; d++) dst[d * 16] = f2bf(oacc[d][r] * inv);
    }
  }
}

// ---------------- host launcher ----------------
extern "C" void kernel_launch(void* const* d_in, const int* in_sizes, int n_in,
                              void* d_out, int out_size, void* d_ws,
                              size_t ws_size, hipStream_t stream) {
  const float* x  = (const float*)d_in[0];
  const float* qw = (const float*)d_in[1];
  const float* qb = (const float*)d_in[2];
  const float* kw = (const float*)d_in[3];
  const float* kb = (const float*)d_in[4];
  const float* vw = (const float*)d_in[5];
  const float* vb = (const float*)d_in[6];
  const float* ow = (const float*)d_in[7];
  const float* ob = (const float*)d_in[8];
  float* out = (float*)d_out;

  // workspace layout (bf16 elements); total 117,440,512 bytes
  unsigned short* xb   = (unsigned short*)d_ws;        // x      [4096][2048]
  unsigned short* wqkv = xb + (size_t)8388608;         // [6144][2048]
  unsigned short* wo   = wqkv + (size_t)12582912;      // [2048][2048]
  unsigned short* qt_  = wo + (size_t)4194304;         // Q  [B,H,S,HD]
  unsigned short* kt_  = qt_ + (size_t)8388608;        // K  [B,H,S,HD]
  unsigned short* vt_  = kt_ + (size_t)8388608;        // V^T[B,H,HD,S]
  unsigned short* ctx  = vt_ + (size_t)8388608;        // ctx[B,S,D]

  cvt_all<<<24576, 256, 0, stream>>>(x, qw, kw, vw, ow, xb, wqkv, wo);

  gemm_qkv<<<768, 512, 147456, stream>>>(xb, wqkv, qb, kb, vb, qt_, kt_, vt_);
  attn_fwd<<<512, 256, 0, stream>>>(qt_, kt_, vt_, ctx);
  gemm_out<<<256, 512, 147456, stream>>>(ctx, wo, ob, out);
}